// Round 9
// baseline (1413.101 us; speedup 1.0000x reference)
//
#include <hip/hip_runtime.h>

typedef unsigned short u16;
typedef __attribute__((ext_vector_type(4))) short s16x4;
typedef __attribute__((ext_vector_type(8))) short s16x8;
typedef __attribute__((ext_vector_type(4))) float f32x4;

__device__ __forceinline__ float bf2f(u16 u) {
    union { unsigned int i; float f; } c; c.i = ((unsigned int)u) << 16; return c.f;
}
__device__ __forceinline__ u16 f2bf(float f) {
    union { float f; unsigned int u; } c; c.f = f;
    unsigned int u = c.u;
    unsigned int r = (u + 0x7fffu + ((u >> 16) & 1u)) >> 16;
    return (u16)r;
}

// ------------- transpose fp32 -> bf16 hi/lo split, 32x32 tiles -------------
__global__ __launch_bounds__(256) void transpose_split_kernel(const float* __restrict__ src,
                                                              u16* __restrict__ dh,
                                                              u16* __restrict__ dl,
                                                              int R, int C) {
    __shared__ float tile[32][33];
    int c0 = blockIdx.x * 32, r0 = blockIdx.y * 32;
    int tx = threadIdx.x & 31, ty = threadIdx.x >> 5;
    for (int i = 0; i < 4; i++)
        tile[ty + 8 * i][tx] = src[(size_t)(r0 + ty + 8 * i) * C + c0 + tx];
    __syncthreads();
    for (int i = 0; i < 4; i++) {
        float v = tile[tx][ty + 8 * i];
        u16 hb = f2bf(v);
        size_t idx = (size_t)(c0 + ty + 8 * i) * R + r0 + tx;
        dh[idx] = hb;
        dl[idx] = f2bf(v - bf2f(hb));
    }
}

// ------------- layernorm fp32 -> bf16 hi/lo split -------------
__global__ __launch_bounds__(256) void ln_split_kernel(const float* __restrict__ x,
                                                       const float* __restrict__ sc,
                                                       const float* __restrict__ bi,
                                                       u16* __restrict__ oh,
                                                       u16* __restrict__ ol) {
    int row = blockIdx.x, tid = threadIdx.x;
    f32x4 u = *(const f32x4*)(x + (size_t)row * 1024 + tid * 4);
    float s = u[0] + u[1] + u[2] + u[3];
    float ss = u[0]*u[0] + u[1]*u[1] + u[2]*u[2] + u[3]*u[3];
    for (int off = 1; off < 64; off <<= 1) { s += __shfl_xor(s, off, 64); ss += __shfl_xor(ss, off, 64); }
    __shared__ float red[8];
    if ((tid & 63) == 0) { red[tid >> 6] = s; red[4 + (tid >> 6)] = ss; }
    __syncthreads();
    s = red[0] + red[1] + red[2] + red[3];
    ss = red[4] + red[5] + red[6] + red[7];
    float mu = s * (1.0f / 1024.0f);
    float rstd = rsqrtf(ss * (1.0f / 1024.0f) - mu * mu + 1e-5f);
    f32x4 g = *(const f32x4*)(sc + tid * 4);
    f32x4 b = *(const f32x4*)(bi + tid * 4);
    for (int i = 0; i < 4; i++) {
        float v = (u[i] - mu) * rstd * g[i] + b[i];
        u16 hb = f2bf(v);
        oh[(size_t)row * 1024 + tid * 4 + i] = hb;
        ol[(size_t)row * 1024 + tid * 4 + i] = f2bf(v - bf2f(hb));
    }
}

// ------------- layernorm fp32 -> bf16 (MoE GEMM input) -------------
__global__ __launch_bounds__(256) void ln_f2b_kernel(const float* __restrict__ x,
                                                     const float* __restrict__ sc,
                                                     const float* __restrict__ bi,
                                                     u16* __restrict__ out) {
    int row = blockIdx.x, tid = threadIdx.x;
    f32x4 u = *(const f32x4*)(x + (size_t)row * 1024 + tid * 4);
    float s = u[0] + u[1] + u[2] + u[3];
    float ss = u[0]*u[0] + u[1]*u[1] + u[2]*u[2] + u[3]*u[3];
    for (int off = 1; off < 64; off <<= 1) { s += __shfl_xor(s, off, 64); ss += __shfl_xor(ss, off, 64); }
    __shared__ float red[8];
    if ((tid & 63) == 0) { red[tid >> 6] = s; red[4 + (tid >> 6)] = ss; }
    __syncthreads();
    s = red[0] + red[1] + red[2] + red[3];
    ss = red[4] + red[5] + red[6] + red[7];
    float mu = s * (1.0f / 1024.0f);
    float rstd = rsqrtf(ss * (1.0f / 1024.0f) - mu * mu + 1e-5f);
    f32x4 g = *(const f32x4*)(sc + tid * 4);
    f32x4 b = *(const f32x4*)(bi + tid * 4);
    u16* op = out + (size_t)row * 1024 + tid * 4;
    for (int i = 0; i < 4; i++)
        op[i] = f2bf((u[i] - mu) * rstd * g[i] + b[i]);
}

// ------------- pre-split GEMM: C = A @ B^T, A/B given as bf16 hi/lo pairs -------------
// 3-term split MFMA (hh + hl + lh). 128x128 tile, BK=32, 4 waves.
// mode 1: fp32 C = acc + res[idx]                          (Wo projection + residual)
// mode 2: QKV fused: sel = n0>>10 picks q/k/v; out = bf16 hi/lo split of acc*scale
__global__ __launch_bounds__(256) void gemm_ps(const u16* __restrict__ Ah, const u16* __restrict__ Al,
                                               const u16* __restrict__ Bh, const u16* __restrict__ Bl,
                                               int M, int N, int K,
                                               float* __restrict__ C, int mode,
                                               const float* __restrict__ res,
                                               u16* __restrict__ qh) {
    __shared__ __align__(16) short Ahs[128 * 32], Als[128 * 32];
    __shared__ __align__(16) short Bhs[128 * 32], Bls[128 * 32];
    int m0 = blockIdx.y * 128, n0 = blockIdx.x * 128;
    int tid = threadIdx.x, lane = tid & 63, w = tid >> 6;
    int wm = (w & 1) * 64, wn = (w >> 1) * 64;
    int lr = lane & 15, lq = lane >> 4;
    f32x4 acc[4][4] = {};

    for (int k0 = 0; k0 < K; k0 += 32) {
        for (int c = tid; c < 512; c += 256) {
            int row = c >> 2, col = (c & 3) * 8;
            size_t ai = (size_t)(m0 + row) * K + k0 + col;
            size_t bi = (size_t)(n0 + row) * K + k0 + col;
            *(s16x8*)&Ahs[row * 32 + col] = *(const s16x8*)&Ah[ai];
            *(s16x8*)&Als[row * 32 + col] = *(const s16x8*)&Al[ai];
            *(s16x8*)&Bhs[row * 32 + col] = *(const s16x8*)&Bh[bi];
            *(s16x8*)&Bls[row * 32 + col] = *(const s16x8*)&Bl[bi];
        }
        __syncthreads();
        s16x8 ah[4], al[4], bh[4], bl[4];
        for (int i = 0; i < 4; i++) {
            int off = (wm + i * 16 + lr) * 32 + lq * 8;
            ah[i] = *(const s16x8*)&Ahs[off];
            al[i] = *(const s16x8*)&Als[off];
        }
        for (int j = 0; j < 4; j++) {
            int off = (wn + j * 16 + lr) * 32 + lq * 8;
            bh[j] = *(const s16x8*)&Bhs[off];
            bl[j] = *(const s16x8*)&Bls[off];
        }
        for (int i = 0; i < 4; i++)
            for (int j = 0; j < 4; j++) {
                acc[i][j] = __builtin_amdgcn_mfma_f32_16x16x32_bf16(al[i], bh[j], acc[i][j], 0, 0, 0);
                acc[i][j] = __builtin_amdgcn_mfma_f32_16x16x32_bf16(ah[i], bl[j], acc[i][j], 0, 0, 0);
                acc[i][j] = __builtin_amdgcn_mfma_f32_16x16x32_bf16(ah[i], bh[j], acc[i][j], 0, 0, 0);
            }
        __syncthreads();
    }

    int sel = n0 >> 10;                       // block-uniform (128 | 1024)
    u16* oh = qh + (size_t)sel * 8388608;     // q/k/v hi base (16 MB apart)
    u16* ol = oh + 4194304;                   // lo = hi + 8 MB
    float scale = (sel == 0) ? 0.125f : 1.0f;
    for (int i = 0; i < 4; i++)
        for (int j = 0; j < 4; j++)
            for (int r = 0; r < 4; r++) {
                int row = m0 + wm + i * 16 + lq * 4 + r;
                int col = n0 + wn + j * 16 + lr;
                float v = acc[i][j][r];
                if (mode == 1) {
                    size_t idx = (size_t)row * N + col;
                    C[idx] = v + res[idx];
                } else {
                    v *= scale;
                    u16 hb = f2bf(v);
                    size_t idx = (size_t)row * 1024 + (col & 1023);
                    oh[idx] = hb;
                    ol[idx] = f2bf(v - bf2f(hb));
                }
            }
}

// ------------- MoE GEMM: C[M,N] = A(bf16)[M,K] @ Bcat(fp32, rows contiguous in n) ------
// mode 2 (up):   B = W1 [E,D,F]; n = e*256+f; bf16 C = relu(acc)*gates[row][n>>8]
// mode 1 (down): B = W2 flat [4096,1024];     fp32 C = acc + res[idx]
__global__ __launch_bounds__(256) void gemm_moe(const u16* __restrict__ A,
                                                const float* __restrict__ B,
                                                int M, int N, int K,
                                                void* __restrict__ C, int mode,
                                                const float* __restrict__ res,
                                                const float* __restrict__ gates) {
    __shared__ __align__(16) short As[128 * 32];
    __shared__ __align__(16) short Bs[128 * 32];
    int m0 = blockIdx.y * 128, n0 = blockIdx.x * 128;
    int tid = threadIdx.x, lane = tid & 63, w = tid >> 6;
    int wm = (w & 1) * 64, wn = (w >> 1) * 64;
    int lr = lane & 15, lq = lane >> 4;
    f32x4 acc[4][4] = {};

    for (int k0 = 0; k0 < K; k0 += 32) {
        for (int c = tid; c < 512; c += 256) {
            int row = c >> 2, col = (c & 3) * 8;
            *(s16x8*)&As[row * 32 + col] = *(const s16x8*)&A[(size_t)(m0 + row) * K + k0 + col];
        }
        {
            int kk = tid >> 3, fseg = (tid & 7) * 16;
            const float* bp;
            if (mode == 2) bp = B + ((size_t)(n0 >> 8) * 1024 + k0 + kk) * 256 + (n0 & 255) + fseg;
            else           bp = B + (size_t)(k0 + kk) * 1024 + n0 + fseg;
            f32x4 b0 = *(const f32x4*)bp, b1 = *(const f32x4*)(bp + 4);
            f32x4 b2 = *(const f32x4*)(bp + 8), b3 = *(const f32x4*)(bp + 12);
            for (int i = 0; i < 4; i++) {
                Bs[(fseg + i)      * 32 + kk] = (short)f2bf(b0[i]);
                Bs[(fseg + 4 + i)  * 32 + kk] = (short)f2bf(b1[i]);
                Bs[(fseg + 8 + i)  * 32 + kk] = (short)f2bf(b2[i]);
                Bs[(fseg + 12 + i) * 32 + kk] = (short)f2bf(b3[i]);
            }
        }
        __syncthreads();
        s16x8 av[4], bv[4];
        for (int i = 0; i < 4; i++) av[i] = *(const s16x8*)&As[(wm + i * 16 + lr) * 32 + lq * 8];
        for (int j = 0; j < 4; j++) bv[j] = *(const s16x8*)&Bs[(wn + j * 16 + lr) * 32 + lq * 8];
        for (int i = 0; i < 4; i++)
            for (int j = 0; j < 4; j++)
                acc[i][j] = __builtin_amdgcn_mfma_f32_16x16x32_bf16(av[i], bv[j], acc[i][j], 0, 0, 0);
        __syncthreads();
    }

    for (int i = 0; i < 4; i++)
        for (int j = 0; j < 4; j++)
            for (int r = 0; r < 4; r++) {
                int row = m0 + wm + i * 16 + lq * 4 + r;
                int col = n0 + wn + j * 16 + lr;
                size_t idx = (size_t)row * N + col;
                float v = acc[i][j][r];
                if (mode == 1) {
                    ((float*)C)[idx] = v + res[idx];
                } else {
                    float g = gates[(size_t)row * 16 + (col >> 8)];
                    ((u16*)C)[idx] = f2bf(fmaxf(v, 0.0f) * g);
                }
            }
}

// ------------- V transpose: v_hi/lo [4096][1024] -> vT_hi/lo [32 bh][64 d][2048 s] -------
__global__ __launch_bounds__(256) void vtrans_kernel(const u16* __restrict__ v_hi,
                                                     const u16* __restrict__ v_lo,
                                                     u16* __restrict__ vT_hi,
                                                     u16* __restrict__ vT_lo) {
    __shared__ __align__(16) short tile[64][72];
    int st = blockIdx.x, bh = blockIdx.y;
    int b = bh >> 4, h = bh & 15;
    int tid = threadIdx.x;
    int i = tid >> 2, seg = (tid & 3) * 16;
    for (int p = 0; p < 2; p++) {
        const u16* src = p ? v_lo : v_hi;
        u16* dst = p ? vT_lo : vT_hi;
        size_t goff = (size_t)(b * 2048 + st * 64 + i) * 1024 + h * 64 + seg;
        *(s16x8*)&tile[i][seg]     = *(const s16x8*)&src[goff];
        *(s16x8*)&tile[i][seg + 8] = *(const s16x8*)&src[goff + 8];
        __syncthreads();
        s16x8 o0, o1;
        for (int j = 0; j < 8; j++) { o0[j] = tile[seg + j][i]; o1[j] = tile[seg + 8 + j][i]; }
        size_t doff = ((size_t)bh * 64 + i) * 2048 + st * 64 + seg;
        *(s16x8*)&dst[doff]     = o0;
        *(s16x8*)&dst[doff + 8] = o1;
        __syncthreads();
    }
}

// ------------- MFMA flash attention via S^T trick, split-bf16 3-term -------------
// grid (32, 32): block = 64 Q rows of one (b,h); 4 waves x 16 rows.
// S^T = K*Q^T (K=32 MFMA): C-layout [key=lq*4+ri][qrow=lr] == B-operand layout of P^T
// for the K=16 MFMA, so PV runs as O^T = V^T * P^T with P straight from registers —
// no LDS round-trip, 2 barriers/chunk. lo*lo terms dropped (~2^-34, negligible).
__global__ __launch_bounds__(256) void attn_mfma(const u16* __restrict__ qh_g,
                                                 const u16* __restrict__ ql_g,
                                                 const u16* __restrict__ kh_g,
                                                 const u16* __restrict__ kl_g,
                                                 const u16* __restrict__ vth_g,
                                                 const u16* __restrict__ vtl_g,
                                                 u16* __restrict__ ch,
                                                 u16* __restrict__ cl) {
    __shared__ __align__(16) short smem[18432];   // Ksh|Ksl|Vsh|Vsl, each 64 rows x 72
    short* Ksh = smem;
    short* Ksl = smem + 4608;
    short* Vsh = smem + 9216;
    short* Vsl = smem + 13824;
    int bh = blockIdx.y, b = bh >> 4, h = bh & 15;
    int tid = threadIdx.x, w = tid >> 6, lane = tid & 63;
    int lr = lane & 15, lq = lane >> 4;
    int qb = blockIdx.x * 64 + w * 16;

    // Q fragments: serve as B operands (B[k=d][n=qrow]) — same lane data as A-layout
    s16x8 qfh[2], qfl[2];
    for (int kc = 0; kc < 2; kc++) {
        size_t qoff = (size_t)(b * 2048 + qb + lr) * 1024 + h * 64 + kc * 32 + lq * 8;
        qfh[kc] = *(const s16x8*)&qh_g[qoff];
        qfl[kc] = *(const s16x8*)&ql_g[qoff];
    }

    float m_ = -1e30f, l_ = 0.0f;     // per qrow=lr (replicated across lq groups)
    f32x4 O[4] = {};                  // O^T C-layout: row=d=nt*16+lq*4+r, col=qrow=lr

    for (int kc0 = 0; kc0 < 2048; kc0 += 64) {
        {   // stage K [key][d] and V^T [d][key]
            int kk = tid >> 2, seg = (tid & 3) * 16;
            size_t goff = (size_t)(b * 2048 + kc0 + kk) * 1024 + h * 64 + seg;
            *(s16x8*)&Ksh[kk * 72 + seg]     = *(const s16x8*)&kh_g[goff];
            *(s16x8*)&Ksh[kk * 72 + seg + 8] = *(const s16x8*)&kh_g[goff + 8];
            *(s16x8*)&Ksl[kk * 72 + seg]     = *(const s16x8*)&kl_g[goff];
            *(s16x8*)&Ksl[kk * 72 + seg + 8] = *(const s16x8*)&kl_g[goff + 8];
            size_t voff = ((size_t)bh * 64 + kk) * 2048 + kc0 + seg;
            *(s16x8*)&Vsh[kk * 72 + seg]     = *(const s16x8*)&vth_g[voff];
            *(s16x8*)&Vsh[kk * 72 + seg + 8] = *(const s16x8*)&vth_g[voff + 8];
            *(s16x8*)&Vsl[kk * 72 + seg]     = *(const s16x8*)&vtl_g[voff];
            *(s16x8*)&Vsl[kk * 72 + seg + 8] = *(const s16x8*)&vtl_g[voff + 8];
        }
        __syncthreads();

        // S^T = K Q^T (3-term split), st[ct] holds keys ct*16+lq*4+ri for qrow=lr
        f32x4 st[4];
        for (int ct = 0; ct < 4; ct++) {
            f32x4 a = {0.0f, 0.0f, 0.0f, 0.0f};
            for (int kc = 0; kc < 2; kc++) {
                s16x8 kbh = *(const s16x8*)&Ksh[(ct * 16 + lr) * 72 + kc * 32 + lq * 8];
                s16x8 kbl = *(const s16x8*)&Ksl[(ct * 16 + lr) * 72 + kc * 32 + lq * 8];
                a = __builtin_amdgcn_mfma_f32_16x16x32_bf16(kbl, qfh[kc], a, 0, 0, 0);
                a = __builtin_amdgcn_mfma_f32_16x16x32_bf16(kbh, qfl[kc], a, 0, 0, 0);
                a = __builtin_amdgcn_mfma_f32_16x16x32_bf16(kbh, qfh[kc], a, 0, 0, 0);
            }
            st[ct] = a;
        }

        // online softmax over keys: in-lane (16) + shuffle over lq groups (2 shuffles)
        float mx = -1e30f;
        for (int ct = 0; ct < 4; ct++)
            for (int ri = 0; ri < 4; ri++) mx = fmaxf(mx, st[ct][ri]);
        mx = fmaxf(mx, __shfl_xor(mx, 16, 64));
        mx = fmaxf(mx, __shfl_xor(mx, 32, 64));
        float mn = fmaxf(m_, mx);
        float a = __expf(m_ - mn);
        m_ = mn;
        float ps = 0.0f;
        s16x4 phv[4], plv[4];
        for (int ct = 0; ct < 4; ct++)
            for (int ri = 0; ri < 4; ri++) {
                float p = __expf(st[ct][ri] - mn);
                ps += p;
                u16 hb = f2bf(p);
                phv[ct][ri] = (short)hb;
                plv[ct][ri] = (short)f2bf(p - bf2f(hb));
            }
        ps += __shfl_xor(ps, 16, 64);
        ps += __shfl_xor(ps, 32, 64);
        l_ = l_ * a + ps;
        for (int nt = 0; nt < 4; nt++) O[nt] *= a;

        // O^T += V^T P^T (K=16 MFMA, P^T from registers; 3-term split)
        for (int nt = 0; nt < 4; nt++)
            for (int kt = 0; kt < 4; kt++) {
                s16x4 vah = *(const s16x4*)&Vsh[(nt * 16 + lr) * 72 + kt * 16 + lq * 4];
                s16x4 val = *(const s16x4*)&Vsl[(nt * 16 + lr) * 72 + kt * 16 + lq * 4];
                O[nt] = __builtin_amdgcn_mfma_f32_16x16x16bf16_1k(vah, plv[kt], O[nt], 0, 0, 0);
                O[nt] = __builtin_amdgcn_mfma_f32_16x16x16bf16_1k(val, phv[kt], O[nt], 0, 0, 0);
                O[nt] = __builtin_amdgcn_mfma_f32_16x16x16bf16_1k(vah, phv[kt], O[nt], 0, 0, 0);
            }
        __syncthreads();
    }

    // epilogue: O^T[d][qrow] -> ctx_hi/lo[qrow][d] via one LDS transpose (per-wave region)
    short* eh = smem + w * 2304;          // 16 rows x 72, hi
    short* el = eh + 1152;                // lo
    float inv = 1.0f / l_;
    for (int nt = 0; nt < 4; nt++)
        for (int r = 0; r < 4; r++) {
            float v = O[nt][r] * inv;
            int d = nt * 16 + lq * 4 + r;
            u16 hb = f2bf(v);
            eh[lr * 72 + d] = (short)hb;
            el[lr * 72 + d] = (short)f2bf(v - bf2f(hb));
        }
    __syncthreads();
    {
        int row = lane >> 2, seg = (lane & 3) * 16;
        size_t g = (size_t)(b * 2048 + qb + row) * 1024 + h * 64 + seg;
        *(s16x8*)&ch[g]     = *(const s16x8*)&eh[row * 72 + seg];
        *(s16x8*)&ch[g + 8] = *(const s16x8*)&eh[row * 72 + seg + 8];
        *(s16x8*)&cl[g]     = *(const s16x8*)&el[row * 72 + seg];
        *(s16x8*)&cl[g + 8] = *(const s16x8*)&el[row * 72 + seg + 8];
    }
}

// ------------- router: pure fp32 (decisions must match fp32 reference) -------------
__global__ __launch_bounds__(256) void router_kernel(const float* __restrict__ x2,
                                                     const float* __restrict__ sc,
                                                     const float* __restrict__ bi,
                                                     const float* __restrict__ Wsel,
                                                     float* __restrict__ gates) {
    int tid = threadIdx.x, w = tid >> 6, lane = tid & 63;
    int t = blockIdx.x * 4 + w;
    const float* xp = x2 + (size_t)t * 1024;
    float s = 0.0f, ss = 0.0f;
    for (int i = 0; i < 16; i++) {
        float v = xp[lane * 16 + i];
        s += v; ss += v * v;
    }
    for (int off = 1; off < 64; off <<= 1) { s += __shfl_xor(s, off, 64); ss += __shfl_xor(ss, off, 64); }
    float mu = s * (1.0f / 1024.0f);
    float rstd = rsqrtf(ss * (1.0f / 1024.0f) - mu * mu + 1e-5f);
    int e = lane & 15, part = lane >> 4;
    float acc = 0.0f;
    for (int d = part * 256; d < part * 256 + 256; d++) {
        float h = (xp[d] - mu) * rstd * sc[d] + bi[d];
        acc += h * Wsel[(size_t)d * 16 + e];
    }
    acc += __shfl_xor(acc, 16, 64);
    acc += __shfl_xor(acc, 32, 64);
    float v = 1.0f / (1.0f + __expf(-acc));
    float m1 = v;
    for (int off = 1; off < 64; off <<= 1) m1 = fmaxf(m1, __shfl_xor(m1, off, 64));
    unsigned long long b1 = __ballot(v == m1);
    int e1 = (__ffsll(b1) - 1) & 15;
    float v2 = (e == e1) ? -1e30f : v;
    float m2 = v2;
    for (int off = 1; off < 64; off <<= 1) m2 = fmaxf(m2, __shfl_xor(m2, off, 64));
    unsigned long long b2 = __ballot(v2 == m2);
    int e2 = (__ffsll(b2) - 1) & 15;
    if (lane < 16)
        gates[(size_t)t * 16 + e] = (e == e1) ? m1 : (e == e2 ? m2 : 0.0f);
}

extern "C" void kernel_launch(void* const* d_in, const int* in_sizes, int n_in,
                              void* d_out, int out_size, void* d_ws, size_t ws_size,
                              hipStream_t stream) {
    const float* x    = (const float*)d_in[0];
    const float* Wq   = (const float*)d_in[1];
    const float* Wk   = (const float*)d_in[2];
    const float* Wv   = (const float*)d_in[3];
    const float* Wo   = (const float*)d_in[4];
    const float* ln1s = (const float*)d_in[5];
    const float* ln1b = (const float*)d_in[6];
    const float* ln2s = (const float*)d_in[7];
    const float* ln2b = (const float*)d_in[8];
    const float* Wsel = (const float*)d_in[9];
    const float* W1   = (const float*)d_in[10];
    const float* W2   = (const float*)d_in[11];
    float* out = (float*)d_out;

    // Workspace (96 MB, liveness-overlaid):
    //  [0,16)  h1_hi[0,8)/h1_lo[8,16) -> vT_hi/vT_lo -> h2[0,8)+gates[8,8.25)
    //  [16,48) q_hi/q_lo/k_hi/k_lo (8 MB each) -> up bf16 after attn
    //  [48,64) v_hi/v_lo -> ctx_hi/ctx_lo after vtrans
    //  [64,80) x2 fp32 (live to end)
    //  [80,92) Wcat_hi[80,86)/Wcat_lo[86,92)  (QKV weights, BT [3072][1024])
    //  [92,96) WoT_hi[92,94)/WoT_lo[94,96)
    char* ws = (char*)d_ws;
    const size_t MB = 1024 * 1024;
    u16*   h1_hi = (u16*)  (ws + 0 * MB);
    u16*   h1_lo = (u16*)  (ws + 8 * MB);
    u16*   vT_hi = (u16*)  (ws + 0 * MB);
    u16*   vT_lo = (u16*)  (ws + 8 * MB);
    u16*   h2    = (u16*)  (ws + 0 * MB);
    float* gates = (float*)(ws + 8 * MB);
    u16*   q_hi  = (u16*)  (ws + 16 * MB);
    u16*   up    = (u16*)  (ws + 16 * MB);
    u16*   v_hi  = (u16*)  (ws + 48 * MB);
    u16*   v_lo  = (u16*)  (ws + 56 * MB);
    u16*   ctx_hi= (u16*)  (ws + 48 * MB);
    u16*   ctx_lo= (u16*)  (ws + 56 * MB);
    float* x2    = (float*)(ws + 64 * MB);
    u16*   Wc_hi = (u16*)  (ws + 80 * MB);
    u16*   Wc_lo = (u16*)  (ws + 86 * MB);
    u16*   Wo_hi = (u16*)  (ws + 92 * MB);
    u16*   Wo_lo = (u16*)  (ws + 94 * MB);
    u16*   k_hi  = q_hi + 8388608;
    u16*   k_lo  = q_hi + 8388608 + 4194304;

    // weight transposes + splits (BT layout)
    transpose_split_kernel<<<dim3(32, 32), 256, 0, stream>>>(Wq, Wc_hi,           Wc_lo,           1024, 1024);
    transpose_split_kernel<<<dim3(32, 32), 256, 0, stream>>>(Wk, Wc_hi + 1048576, Wc_lo + 1048576, 1024, 1024);
    transpose_split_kernel<<<dim3(32, 32), 256, 0, stream>>>(Wv, Wc_hi + 2097152, Wc_lo + 2097152, 1024, 1024);
    transpose_split_kernel<<<dim3(32, 32), 256, 0, stream>>>(Wo, Wo_hi,           Wo_lo,           1024, 1024);

    // LN1 -> h1 hi/lo
    ln_split_kernel<<<4096, 256, 0, stream>>>(x, ln1s, ln1b, h1_hi, h1_lo);
    // fused QKV projection (N=3072) -> q/k/v hi/lo splits (Q pre-scaled by 1/8)
    gemm_ps<<<dim3(24, 32), 256, 0, stream>>>(h1_hi, h1_lo, Wc_hi, Wc_lo, 4096, 3072, 1024,
                                              nullptr, 2, nullptr, q_hi);
    // V -> V^T per (b,h)
    vtrans_kernel<<<dim3(32, 32), 256, 0, stream>>>(v_hi, v_lo, vT_hi, vT_lo);
    // MFMA flash attention -> ctx hi/lo (overlays v_hi/v_lo)
    attn_mfma<<<dim3(32, 32), 256, 0, stream>>>(q_hi, q_hi + 4194304, k_hi, k_lo,
                                                vT_hi, vT_lo, ctx_hi, ctx_lo);
    // output projection + residual -> x2 fp32
    gemm_ps<<<dim3(8, 32), 256, 0, stream>>>(ctx_hi, ctx_lo, Wo_hi, Wo_lo, 4096, 1024, 1024,
                                             x2, 1, x, nullptr);
    // LN2 -> h2 bf16
    ln_f2b_kernel<<<4096, 256, 0, stream>>>(x2, ln2s, ln2b, h2);
    // router -> gates
    router_kernel<<<1024, 256, 0, stream>>>(x2, ln2s, ln2b, Wsel, gates);
    // MoE up (dense, relu*gate) -> up bf16
    gemm_moe<<<dim3(32, 32), 256, 0, stream>>>(h2, W1, 4096, 4096, 1024, up, 2, nullptr, gates);
    // MoE down + residual -> out fp32
    gemm_moe<<<dim3(8, 32), 256, 0, stream>>>(up, W2, 4096, 1024, 4096, out, 1, x2, nullptr);
}